// Round 5
// baseline (313.322 us; speedup 1.0000x reference)
//
#include <hip/hip_runtime.h>

// HadamardAdapter, fully analytic (H = Sylvester/64, orthogonal):
//   out[row,d] = x[row,d] + wloc[row][d&31] - wbar[d&31]
//   y[row][m]   = sum_{d&31==m} x[row,d]
//   cz[row][j]  = s_j*(1/64)*sum_m y[row][m]*(-1)^popc(j&m), s_j = leaky(adapter_j)
//   wloc/wbar   = (1/64) * inverse 32-pt transform of (cz - czbar)
// Single persistent kernel (minimal HBM traffic: 128 MB read + 128 MB write;
// phase-2 re-read of x is L3-resident — proven by round-3 counters).
// Grid barrier polls RELAXED (acquire-per-poll emitted buffer_inv storms that
// throttled co-resident streaming waves: round-3 4x regression). One fence after.

#define NROWS 8192
#define DDIM  4096
#define NK    24
#define NBLK  1024
#define RPB   8            // rows per block

typedef float v4f __attribute__((ext_vector_type(4)));

__global__ __launch_bounds__(256, 4) void hada_fused(
    const float* __restrict__ x, const float* __restrict__ adapter,
    float* __restrict__ out, float* __restrict__ Y, unsigned* __restrict__ cnt)
{
    __shared__ __align__(16) float y[RPB][32];
    __shared__ float cz[RPB][NK];
    __shared__ float czb[NK];
    __shared__ __align__(16) float wsh[RPB][32];
    __shared__ float Ysh[32];

    const int t = threadIdx.x;
    const int wave = t >> 6, lane = t & 63;
    const int blk = blockIdx.x;

    // ---------- Phase 1: fold rows (one wave per row, 2 rows per wave) ------
    for (int rr = 0; rr < 2; ++rr) {
        const int r = wave * 2 + rr;
        const size_t row = (size_t)blk * RPB + r;
        const v4f* __restrict__ xr = (const v4f*)x + row * (DDIM / 4);
        v4f acc = (v4f)0.f;
#pragma unroll
        for (int i = 0; i < 16; ++i) acc += xr[lane + 64 * i];
        // lane's float4 residues: m = 4*(lane&7)+c  (256 floats/iter ≡ 0 mod 32)
#pragma unroll
        for (int off = 8; off < 64; off <<= 1) {
            acc.x += __shfl_xor(acc.x, off);
            acc.y += __shfl_xor(acc.y, off);
            acc.z += __shfl_xor(acc.z, off);
            acc.w += __shfl_xor(acc.w, off);
        }
        if (lane < 8) *(v4f*)&y[r][lane * 4] = acc;
    }
    __syncthreads();

    if (t < RPB * NK) {                       // per-row cz
        const int r = t / NK, j = t % NK;
        float zv = 0.f;
#pragma unroll
        for (int m = 0; m < 32; ++m)
            zv += (__popc(j & m) & 1) ? -y[r][m] : y[r][m];
        zv *= (1.f / 64.f);
        const float a = adapter[j];
        const float sc = (a > 0.f) ? a : 0.01f * a;   // leaky_relu slope 0.01
        cz[r][j] = sc * zv;
    }
    if (t >= 192 && t < 224) {                // block partial -> global Y
        const int m = t - 192;
        float s = 0.f;
#pragma unroll
        for (int r = 0; r < RPB; ++r) s += y[r][m];
        atomicAdd(&Y[m], s);
    }

    // ---------- Grid barrier (relaxed polling, single fence on exit) --------
    __threadfence();                           // release our Y contributions
    __syncthreads();
    if (t == 0) {
        atomicAdd(cnt, 1u);
        while (__hip_atomic_load(cnt, __ATOMIC_RELAXED, __HIP_MEMORY_SCOPE_AGENT) < NBLK)
            __builtin_amdgcn_s_sleep(8);
    }
    __syncthreads();
    __threadfence();                           // acquire once (not per poll)

    // ---------- Phase 2: wbar (redundant per block), per-row w, apply -------
    if (t < 32)
        Ysh[t] = __hip_atomic_load(&Y[t], __ATOMIC_RELAXED, __HIP_MEMORY_SCOPE_AGENT);
    __syncthreads();
    if (t < NK) {
        float zb = 0.f;
#pragma unroll
        for (int m = 0; m < 32; ++m)
            zb += (__popc(t & m) & 1) ? -Ysh[m] : Ysh[m];
        zb *= (1.f / 64.f) / (float)NROWS;
        const float a = adapter[t];
        const float sc = (a > 0.f) ? a : 0.01f * a;
        czb[t] = sc * zb;
    }
    __syncthreads();
    {
        const int r = t >> 5, m = t & 31;     // 256 threads = 8 rows x 32 bins
        float wv = 0.f;
#pragma unroll
        for (int j = 0; j < NK; ++j) {
            const float c = cz[r][j] - czb[j];
            wv += (__popc(j & m) & 1) ? -c : c;
        }
        wsh[r][m] = wv * (1.f / 64.f);
    }
    __syncthreads();

    for (int rr = 0; rr < 2; ++rr) {
        const int r = wave * 2 + rr;
        const size_t row = (size_t)blk * RPB + r;
        const v4f* __restrict__ xr = (const v4f*)x + row * (DDIM / 4);
        v4f* __restrict__ orow = (v4f*)out + row * (DDIM / 4);
        const v4f w4 = *(const v4f*)&wsh[r][(lane & 7) * 4];
#pragma unroll
        for (int i = 0; i < 16; ++i)
            __builtin_nontemporal_store(xr[lane + 64 * i] + w4, &orow[lane + 64 * i]);
    }
}

extern "C" void kernel_launch(void* const* d_in, const int* in_sizes, int n_in,
                              void* d_out, int out_size, void* d_ws, size_t ws_size,
                              hipStream_t stream) {
    const float* x       = (const float*)d_in[0];   // (4,2048,4096) f32
    const float* adapter = (const float*)d_in[1];   // (24,) f32
    float* out = (float*)d_out;
    float* Y   = (float*)d_ws;                      // [32] global fold
    unsigned* cnt = (unsigned*)((char*)d_ws + 128); // barrier counter

    hipMemsetAsync(d_ws, 0, 256, stream);           // zero Y + cnt each call
    hipLaunchKernelGGL(hada_fused, dim3(NBLK), dim3(256), 0, stream,
                       x, adapter, out, Y, cnt);
}

// Round 6
// 84.659 us; speedup vs baseline: 3.7010x; 3.7010x over previous
//
#include <hip/hip_runtime.h>

// HadamardAdapter, fully analytic (H = Sylvester/64, orthogonal):
//   out[row,d] = x[row,d] + w[row][d&31],
//   y[row][m]  = sum_{d&31==m} x[row,d]
//   z'_j       = FWHT32(y)_j = sum_m (-1)^popc(j&m) y[m]        (z_j = z'_j/64)
//   c_j        = s_j*z'_j/64 - czb_j   (j<24; 0 else),  s_j = leaky(adapter_j)
//   w[m]       = FWHT32(c)_m / 64
//   czb_j      = s_j * FWHT32(Y)_j / (64*NROWS),  Y[m] = global fold (kernel 1)
// Apply is fully wave-local: FWHT via 5-stage shfl_xor butterflies — no LDS,
// no __syncthreads, one wave per row. (Persistent-kernel grid barrier was
// 4x slower for unresolved reasons — rounds 3/5; kernel boundary is the barrier.)

#define NROWS 8192
#define DDIM  4096
#define NK    24
#define K1_BLOCKS 2048
#define K1_THREADS 256

typedef float v4f __attribute__((ext_vector_type(4)));

// ---------------- K1: global 32-residue fold -> Y[32] ------------------------
__global__ __launch_bounds__(256) void hada_fold(const float* __restrict__ x,
                                                 float* __restrict__ Y)
{
    const int t = threadIdx.x;
    const int gtid = blockIdx.x * K1_THREADS + t;
    const v4f* __restrict__ xv = (const v4f*)x;
    v4f acc = (v4f)0.f;
    // 8388608 float4s; stride 524288 (mult of 8 => residues fixed per thread).
#pragma unroll
    for (int i = 0; i < 16; ++i)
        acc += xv[(size_t)i * (K1_BLOCKS * K1_THREADS) + gtid];

#pragma unroll
    for (int off = 8; off < 64; off <<= 1) {
        acc.x += __shfl_xor(acc.x, off);
        acc.y += __shfl_xor(acc.y, off);
        acc.z += __shfl_xor(acc.z, off);
        acc.w += __shfl_xor(acc.w, off);
    }
    __shared__ v4f yp[4][8];
    const int wave = t >> 6, lane = t & 63;
    if (lane < 8) yp[wave][lane] = acc;
    __syncthreads();
    if (t < 32) {
        float s = 0.f;
#pragma unroll
        for (int w = 0; w < 4; ++w) s += yp[w][t >> 2][t & 3];
        atomicAdd(&Y[t], s);   // 2048 adds per address: negligible
    }
}

// ---------------- K2: wave-per-row apply, all-shuffle, no barriers -----------
__global__ __launch_bounds__(256) void hada_apply(const float* __restrict__ x,
                                                  const float* __restrict__ adapter,
                                                  const float* __restrict__ Y,
                                                  float* __restrict__ out)
{
    const int t = threadIdx.x;
    const int lane = t & 63;
    const int wave = t >> 6;
    const int m = lane & 31;                  // halves duplicate all 32-lane math
    const size_t row = (size_t)blockIdx.x * 4 + wave;
    const v4f* __restrict__ xr   = (const v4f*)x   + row * (DDIM / 4);
    v4f*       __restrict__ orow = (v4f*)      out + row * (DDIM / 4);

    // ---- per-wave constants: czb_j in lane j (j = lane&31) ----
    float a  = (m < NK) ? adapter[m] : 0.f;
    float sc = (a > 0.f) ? a : 0.01f * a;     // leaky_relu slope 0.01
    if (m >= NK) sc = 0.f;
    float yg = Y[m];
#pragma unroll
    for (int off = 1; off < 32; off <<= 1) {  // FWHT32: lane j -> sum_m ±Y[m]
        float p = __shfl_xor(yg, off);
        yg = (lane & off) ? (p - yg) : (yg + p);
    }
    const float czb = sc * yg * ((1.f / 64.f) / (float)NROWS);

    // ---- load row (held in regs), fold to 32 residues ----
    v4f v[16];
    v4f acc = (v4f)0.f;
#pragma unroll
    for (int i = 0; i < 16; ++i) { v[i] = xr[lane + 64 * i]; acc += v[i]; }
    // lane's v4f residues: 4*(lane&7)+{0..3}; reduce lanes sharing (lane&7)
#pragma unroll
    for (int off = 8; off < 64; off <<= 1) {
        acc.x += __shfl_xor(acc.x, off);
        acc.y += __shfl_xor(acc.y, off);
        acc.z += __shfl_xor(acc.z, off);
        acc.w += __shfl_xor(acc.w, off);
    }
    // scatter: lane gets y[m] = component (m&3) of acc in lane (m>>2)
    const int src = m >> 2;
    const float c0 = __shfl(acc.x, src);
    const float c1 = __shfl(acc.y, src);
    const float c2 = __shfl(acc.z, src);
    const float c3 = __shfl(acc.w, src);
    const float ylo = (m & 1) ? c1 : c0;
    const float yhi = (m & 1) ? c3 : c2;
    float ym = (m & 2) ? yhi : ylo;

    // ---- FWHT: lane j holds z'_j = 64*z_j ----
#pragma unroll
    for (int off = 1; off < 32; off <<= 1) {
        float p = __shfl_xor(ym, off);
        ym = (lane & off) ? (p - ym) : (ym + p);
    }
    float c = sc * ym * (1.f / 64.f) - czb;   // Δ_j (0 for j>=24: sc=0 => czb=0)

    // ---- inverse FWHT: lane m holds 64*w_m ----
#pragma unroll
    for (int off = 1; off < 32; off <<= 1) {
        float p = __shfl_xor(c, off);
        c = (lane & off) ? (p - c) : (c + p);
    }
    const float wm = c * (1.f / 64.f);

    // gather per-thread w4 for residues 4*(lane&7)+{0..3}
    const int b = (lane & 7) << 2;
    v4f w4;
    w4.x = __shfl(wm, b);
    w4.y = __shfl(wm, b + 1);
    w4.z = __shfl(wm, b + 2);
    w4.w = __shfl(wm, b + 3);

#pragma unroll
    for (int i = 0; i < 16; ++i)
        __builtin_nontemporal_store(v[i] + w4, &orow[lane + 64 * i]);
}

extern "C" void kernel_launch(void* const* d_in, const int* in_sizes, int n_in,
                              void* d_out, int out_size, void* d_ws, size_t ws_size,
                              hipStream_t stream) {
    const float* x       = (const float*)d_in[0];   // (4,2048,4096) f32
    const float* adapter = (const float*)d_in[1];   // (24,) f32
    float* out = (float*)d_out;
    float* Y   = (float*)d_ws;                      // [32] global fold

    hipMemsetAsync(Y, 0, 32 * sizeof(float), stream);
    hipLaunchKernelGGL(hada_fold,  dim3(K1_BLOCKS), dim3(K1_THREADS), 0, stream, x, Y);
    hipLaunchKernelGGL(hada_apply, dim3(NROWS / 4), dim3(256),        0, stream,
                       x, adapter, Y, out);
}